// Round 5
// baseline (282.577 us; speedup 1.0000x reference)
//
#include <hip/hip_runtime.h>

typedef unsigned short ushort_t;
typedef __bf16 bf16_t;
typedef float floatx4 __attribute__((ext_vector_type(4)));
typedef bf16_t bf16x8 __attribute__((ext_vector_type(8)));
typedef float f32x4 __attribute__((ext_vector_type(4)));
typedef unsigned short u16x4 __attribute__((ext_vector_type(4)));
typedef unsigned int u32x2 __attribute__((ext_vector_type(2)));

#define NTOK 4096
#define NHEAD 12
#define HD 64
#define DMODEL 768
#define NROWS 8192  // 2*4096
#define NBH 24

__device__ __forceinline__ ushort_t f2bf(float f) {
  union { float f; unsigned u; } v; v.f = f;
  unsigned u = v.u;
  unsigned r = u + 0x7fffu + ((u >> 16) & 1u);
  return (ushort_t)(r >> 16);
}

__device__ __forceinline__ float bf2f(ushort_t s) {
  union { unsigned u; float f; } v; v.u = (unsigned)s << 16; return v.f;
}

__device__ __forceinline__ void async16(const void* g, void* l) {
  __builtin_amdgcn_global_load_lds(
      (const __attribute__((address_space(1))) void*)g,
      (__attribute__((address_space(3))) void*)l, 16, 0, 0);
}

// ---------------- converters ----------------

__global__ __launch_bounds__(256) void transpose_w4(
    const float* __restrict__ s0, const float* __restrict__ s1,
    const float* __restrict__ s2, const float* __restrict__ s3,
    ushort_t* __restrict__ d_qkv, ushort_t* __restrict__ d_o) {
  __shared__ float t[32][33];
  const int m = blockIdx.z;
  const float* src = (m == 0) ? s0 : (m == 1) ? s1 : (m == 2) ? s2 : s3;
  ushort_t* dst = (m < 3) ? (d_qkv + (size_t)m * DMODEL * DMODEL) : d_o;
  const int bi = blockIdx.x, bj = blockIdx.y;
  const int r = threadIdx.x >> 5, c = threadIdx.x & 31;
  for (int p = 0; p < 4; ++p)
    t[r + p * 8][c] = src[(size_t)(bi * 32 + r + p * 8) * DMODEL + bj * 32 + c];
  __syncthreads();
  for (int p = 0; p < 4; ++p)
    dst[(size_t)(bj * 32 + r + p * 8) * DMODEL + bi * 32 + c] = f2bf(t[c][r + p * 8]);
}

__global__ void convert_x(const float* __restrict__ in, ushort_t* __restrict__ out) {
  int idx = blockIdx.x * 256 + threadIdx.x;
  f32x4 v = ((const f32x4*)in)[idx];
  u16x4 o;
  o.x = f2bf(v.x); o.y = f2bf(v.y); o.z = f2bf(v.z); o.w = f2bf(v.w);
  ((u16x4*)out)[idx] = o;
}

// ---------------- GEMM: C[M x N] = A[M x K] * B^T (B stored [N][K]) ----------------
// mode 0: QKV epilogue. Q scaled (1/8)*log2(e) -> [bh][n][64]; K -> [bh][n][64];
//         V -> TRANSPOSED [bh][64][n]. mode 1: bias + fp32 store.
__global__ __launch_bounds__(256) void gemm_bt(
    const ushort_t* __restrict__ A, const ushort_t* __restrict__ B, int K, int mode,
    ushort_t* __restrict__ q_ws, ushort_t* __restrict__ k_ws, ushort_t* __restrict__ v_ws,
    float* __restrict__ outF, const float* __restrict__ bias) {
  __shared__ __align__(16) ushort_t a_lds[128 * 32];
  __shared__ __align__(16) ushort_t b_lds[128 * 32];
  const int tid = threadIdx.x;
  const int w = tid >> 6, lane = tid & 63;
  const int quad = lane >> 4, l16 = lane & 15;
  const int wm = w >> 1, wn = w & 1;
  const size_t row0 = (size_t)blockIdx.x * 128;
  const size_t col0 = (size_t)blockIdx.y * 128;

  const int srow = w * 32 + (lane >> 2);
  const int kbyte = (lane & 3) * 16;
  const char* aG = (const char*)(A + (row0 + srow) * (size_t)K) + kbyte;
  const char* bG = (const char*)(B + (col0 + srow) * (size_t)K) + kbyte;
  const size_t rstep = (size_t)16 * K * 2;
  char* aL = (char*)a_lds + (size_t)(w * 2) * 1024;
  char* bL = (char*)b_lds + (size_t)(w * 2) * 1024;

  floatx4 acc[4][4];
  for (int i = 0; i < 4; ++i)
    for (int j = 0; j < 4; ++j) acc[i][j] = (floatx4){0.f, 0.f, 0.f, 0.f};

  const int nk = K / 32;
  for (int kt = 0; kt < nk; ++kt) {
    const size_t koff = (size_t)kt * 64;
    __syncthreads();
    async16(aG + koff, aL);
    async16(aG + koff + rstep, aL + 1024);
    async16(bG + koff, bL);
    async16(bG + koff + rstep, bL + 1024);
    __syncthreads();
    bf16x8 af[4], bfr[4];
    for (int mt = 0; mt < 4; ++mt)
      af[mt] = *(bf16x8*)&a_lds[(wm * 64 + mt * 16 + l16) * 32 + quad * 8];
    for (int nt = 0; nt < 4; ++nt)
      bfr[nt] = *(bf16x8*)&b_lds[(wn * 64 + nt * 16 + l16) * 32 + quad * 8];
    for (int mt = 0; mt < 4; ++mt)
      for (int nt = 0; nt < 4; ++nt)
        acc[mt][nt] = __builtin_amdgcn_mfma_f32_16x16x32_bf16(af[mt], bfr[nt], acc[mt][nt], 0, 0, 0);
  }

  if (mode == 0) {
    const int which = (int)(col0 / DMODEL);
    if (which < 2) {
      ushort_t* dstT = (which == 0) ? q_ws : k_ws;
      // Q: fold softmax scale 1/8 AND log2(e) so attention uses native exp2.
      const float scale = (which == 0) ? 0.125f * 1.4426950408889634f : 1.0f;
      for (int mt = 0; mt < 4; ++mt) {
        int gr = (int)row0 + wm * 64 + mt * 16 + quad * 4;
        int b = gr >> 12;
        int n0 = gr & 4095;
        for (int nt = 0; nt < 4; ++nt) {
          int gc = (int)col0 + wn * 64 + nt * 16 + l16;
          int cc = gc - which * DMODEL;
          int h = cc >> 6, d = cc & 63;
          size_t base = ((size_t)(b * NHEAD + h) * NTOK + n0) * HD + d;
          for (int r = 0; r < 4; ++r)
            dstT[base + (size_t)r * HD] = f2bf(acc[mt][nt][r] * scale);
        }
      }
    } else {  // V transposed [bh][d][token]
      for (int mt = 0; mt < 4; ++mt) {
        int gr = (int)row0 + wm * 64 + mt * 16 + quad * 4;
        int b = gr >> 12;
        int n0 = gr & 4095;
        for (int nt = 0; nt < 4; ++nt) {
          int gc = (int)col0 + wn * 64 + nt * 16 + l16;
          int cc = gc - 2 * DMODEL;
          int h = cc >> 6, d = cc & 63;
          u16x4 ov;
          for (int r = 0; r < 4; ++r) ov[r] = f2bf(acc[mt][nt][r]);
          *(u16x4*)&v_ws[((size_t)(b * NHEAD + h) * HD + d) * NTOK + n0] = ov;
        }
      }
    }
  } else {
    for (int mt = 0; mt < 4; ++mt) {
      int gr = (int)row0 + wm * 64 + mt * 16 + quad * 4;
      for (int nt = 0; nt < 4; ++nt) {
        int gc = (int)col0 + wn * 64 + nt * 16 + l16;
        float bv = bias[gc];
        for (int r = 0; r < 4; ++r)
          outF[(size_t)(gr + r) * DMODEL + gc] = acc[mt][nt][r] + bv;
      }
    }
  }
}

// ---------------- flash attention v5: K-split x2, BQ=128, 4 waves ----------------
// Fixed-max softmax => disjoint key-range partials combine by addition.
// grid (24 bh, 16 qpair, 2 split); id = bh + 24*(...) keeps XCD = bh%8 homing.
// Block does qtiles y and 31-y; contiguous half-split => 33 BK64 iters, uniform.
// Partial o (unnormalized, bf16) + l (fp32) -> combine kernel.
__global__ __launch_bounds__(256) void attn5(
    const ushort_t* __restrict__ Qh, const ushort_t* __restrict__ Kh,
    const ushort_t* __restrict__ Vt, ushort_t* __restrict__ o_part,
    float* __restrict__ l_part) {
  __shared__ __align__(16) ushort_t k_lds[2][8 * 512];   // A-frag linear, dbuf
  __shared__ __align__(16) ushort_t v_lds[2][8 * 512];   // B-frag linear (V^T), dbuf
  __shared__ __align__(16) ushort_t q_lds[16 * 512];     // Q stage; reused as P region
  const int tid = threadIdx.x;
  const int w = tid >> 6, lane = tid & 63;
  const int quad = lane >> 4, l16 = lane & 15;
  const int bh = blockIdx.x;   // XCD = bh % 8
  const int split = blockIdx.z;
  const size_t hbase = (size_t)bh * NTOK * HD;
  const ushort_t* Qb = Qh + hbase;
  const ushort_t* Kb = Kh + hbase;
  const ushort_t* Vb = Vt + hbase;  // [64][4096]
  const size_t obase = ((size_t)split * NBH + bh) * NTOK * HD;
  const size_t lbase = ((size_t)split * NBH + bh) * NTOK;

  for (int phase = 0; phase < 2; ++phase) {
    const int qt = (phase == 0) ? (int)blockIdx.y : 31 - (int)blockIdx.y;
    const int Q0 = qt * 128;
    const int nkt = 2 * qt + 2;
    const int kt_lo = (split == 0) ? 0 : nkt / 2;
    const int kt_hi = (split == 0) ? nkt / 2 : nkt;
    const int nit = kt_hi - kt_lo;  // >= 1 always
    __syncthreads();  // protect q/p + k/v regions across phases
    // stage Q: 16 slots (s>>1 = 16-row group, s&1 = d-half)
#pragma unroll
    for (int i = 0; i < 4; ++i) {
      int s = w * 4 + i;
      async16(Qb + (size_t)(Q0 + (s >> 1) * 16 + l16) * HD + (s & 1) * 32 + quad * 8,
              (char*)q_lds + s * 1024);
    }
    // prefetch first tile into buf0
    {
      const int k0p = kt_lo * 64;
#pragma unroll
      for (int i = 0; i < 2; ++i) {
        int s = w * 2 + i;
        async16(Kb + (size_t)(k0p + (s >> 1) * 16 + l16) * HD + (s & 1) * 32 + quad * 8,
                (char*)k_lds + s * 1024);
        async16(Vb + (size_t)((s >> 1) * 16 + l16) * NTOK + k0p + (s & 1) * 32 + quad * 8,
                (char*)v_lds + s * 1024);
      }
    }
    __asm volatile("s_waitcnt vmcnt(0)" ::: "memory");
    bf16x8 qr[2][2];  // own wave's Q slots -> no barrier needed
#pragma unroll
    for (int qf = 0; qf < 2; ++qf)
#pragma unroll
      for (int hh = 0; hh < 2; ++hh)
        qr[qf][hh] = *(const bf16x8*)((const char*)q_lds + ((w * 4 + qf * 2 + hh) * 1024) + lane * 16);

    floatx4 o[2][4];
    float lp[2] = {0.f, 0.f};
#pragma unroll
    for (int qf = 0; qf < 2; ++qf)
#pragma unroll
      for (int dt = 0; dt < 4; ++dt) o[qf][dt] = (floatx4){0.f, 0.f, 0.f, 0.f};

    const int wq0 = Q0 + w * 32;

    for (int it = 0; it < nit; ++it) {
      const int kt = kt_lo + it;
      const int cur = it & 1;
      __syncthreads();  // buf[cur] ready + all waves done with buf[cur^1]
      if (it + 1 < nit) {
        const int k1 = (kt + 1) * 64;
#pragma unroll
        for (int i = 0; i < 2; ++i) {
          int s = w * 2 + i;
          async16(Kb + (size_t)(k1 + (s >> 1) * 16 + l16) * HD + (s & 1) * 32 + quad * 8,
                  (char*)k_lds + (cur ^ 1) * 8192 + s * 1024);
          async16(Vb + (size_t)((s >> 1) * 16 + l16) * NTOK + k1 + (s & 1) * 32 + quad * 8,
                  (char*)v_lds + (cur ^ 1) * 8192 + s * 1024);
        }
      }
      const int k0 = kt * 64;
      if (k0 > wq0 + 31) continue;  // fully above this wave's diagonal (no barrier below)
      const char* kb = (const char*)k_lds + cur * 8192;
      const char* vb = (const char*)v_lds + cur * 8192;

      // S^T = K . Q^T : lane holds (key = mt*16 + quad*4 + r, q = l16)
      floatx4 st[2][4];
#pragma unroll
      for (int mt = 0; mt < 4; ++mt) {
        bf16x8 kf0 = *(const bf16x8*)(kb + (mt * 2 + 0) * 1024 + lane * 16);
        bf16x8 kf1 = *(const bf16x8*)(kb + (mt * 2 + 1) * 1024 + lane * 16);
#pragma unroll
        for (int qf = 0; qf < 2; ++qf) {
          floatx4 z = (floatx4){0.f, 0.f, 0.f, 0.f};
          z = __builtin_amdgcn_mfma_f32_16x16x32_bf16(kf0, qr[qf][0], z, 0, 0, 0);
          z = __builtin_amdgcn_mfma_f32_16x16x32_bf16(kf1, qr[qf][1], z, 0, 0, 0);
          st[qf][mt] = z;
        }
      }
      const bool need_mask = (k0 + 63 > wq0);  // diagonal tile for this wave
#pragma unroll
      for (int qf = 0; qf < 2; ++qf) {
        const int qg = wq0 + qf * 16 + l16;
        float sum = 0.f;
#pragma unroll
        for (int mt = 0; mt < 4; ++mt) {
          float p[4];
#pragma unroll
          for (int r = 0; r < 4; ++r) {
            float e = __builtin_exp2f(st[qf][mt][r]);  // Q pre-scaled by log2(e)/8
            if (need_mask && (k0 + mt * 16 + quad * 4 + r > qg)) e = 0.f;
            p[r] = e;
            sum += e;
          }
          union { float f; unsigned u; } c0, c1, c2, c3;
          c0.f = p[0]; c1.f = p[1]; c2.f = p[2]; c3.f = p[3];
          u32x2 pk;
          pk.x = __builtin_amdgcn_perm(c1.u, c0.u, 0x07060302u);  // [c1.hi16|c0.hi16]
          pk.y = __builtin_amdgcn_perm(c3.u, c2.u, 0x07060302u);
          char* dst = (char*)q_lds + ((w * 4 + qf * 2 + (mt >> 1)) * 1024)
                      + ((((mt & 1) * 2 + (quad >> 1)) * 16 + l16) * 16) + (quad & 1) * 8;
          *(u32x2*)dst = pk;
        }
        lp[qf] += sum;
      }
      __asm volatile("s_waitcnt lgkmcnt(0)" ::: "memory");
      bf16x8 pf[2][2];
#pragma unroll
      for (int qf = 0; qf < 2; ++qf)
#pragma unroll
        for (int hh = 0; hh < 2; ++hh)
          pf[qf][hh] = *(const bf16x8*)((const char*)q_lds + ((w * 4 + qf * 2 + hh) * 1024) + lane * 16);
#pragma unroll
      for (int dt = 0; dt < 4; ++dt) {
        bf16x8 vf0 = *(const bf16x8*)(vb + (dt * 2 + 0) * 1024 + lane * 16);
        bf16x8 vf1 = *(const bf16x8*)(vb + (dt * 2 + 1) * 1024 + lane * 16);
#pragma unroll
        for (int qf = 0; qf < 2; ++qf) {
          o[qf][dt] = __builtin_amdgcn_mfma_f32_16x16x32_bf16(pf[qf][0], vf0, o[qf][dt], 0, 0, 0);
          o[qf][dt] = __builtin_amdgcn_mfma_f32_16x16x32_bf16(pf[qf][1], vf1, o[qf][dt], 0, 0, 0);
        }
      }
    }

    // epilogue: write UNNORMALIZED partial o (bf16) + per-row l (fp32)
#pragma unroll
    for (int qf = 0; qf < 2; ++qf) {
      float lf = lp[qf];
      lf += __shfl_xor(lf, 16);
      lf += __shfl_xor(lf, 32);
#pragma unroll
      for (int r = 0; r < 4; ++r) {
        float lq = __shfl(lf, quad * 4 + r);
        int qg = wq0 + qf * 16 + quad * 4 + r;
        size_t base = obase + (size_t)qg * HD;
#pragma unroll
        for (int dt = 0; dt < 4; ++dt)
          o_part[base + dt * 16 + l16] = f2bf(o[qf][dt][r]);
        if (l16 == 0) l_part[lbase + qg] = lq;
      }
    }
  }
}

// ---------------- combine: ctx = (o0 + o1) / (l0 + l1) ----------------
// 16 rows/block, 16 threads/row x 4 d each.
__global__ __launch_bounds__(256) void combine(
    const ushort_t* __restrict__ o_part, const float* __restrict__ l_part,
    ushort_t* __restrict__ ctx) {
  const int row = blockIdx.x * 16 + (threadIdx.x >> 4);  // [0, 24*4096)
  const int d = (threadIdx.x & 15) * 4;
  const int bh = row >> 12, n = row & 4095;
  const int b = bh / NHEAD, h = bh % NHEAD;
  const size_t i0 = (size_t)row * HD + d;
  const size_t i1 = i0 + (size_t)NBH * NTOK * HD;
  u16x4 a = *(const u16x4*)&o_part[i0];
  u16x4 c = *(const u16x4*)&o_part[i1];
  float inv = 1.0f / (l_part[row] + l_part[row + NBH * NTOK]);
  u16x4 ov;
#pragma unroll
  for (int j = 0; j < 4; ++j) ov[j] = f2bf((bf2f(a[j]) + bf2f(c[j])) * inv);
  *(u16x4*)&ctx[((size_t)b * NTOK + n) * DMODEL + h * HD + d] = ov;
}

// ---------------- launch ----------------
extern "C" void kernel_launch(void* const* d_in, const int* in_sizes, int n_in,
                              void* d_out, int out_size, void* d_ws, size_t ws_size,
                              hipStream_t stream) {
  const float* x  = (const float*)d_in[0];
  const float* wq = (const float*)d_in[1];
  const float* wk = (const float*)d_in[2];
  const float* wv = (const float*)d_in[3];
  const float* wo = (const float*)d_in[4];
  const float* bo = (const float*)d_in[5];
  float* out = (float*)d_out;

  ushort_t* ws = (ushort_t*)d_ws;
  ushort_t* wqkvT = ws;                               // 2304*768
  ushort_t* woutT = wqkvT + 2304 * 768;               // 768*768
  ushort_t* xbf   = woutT + 768 * 768;                // 8192*768 (x bf16; reused as ctx)
  ushort_t* qh    = xbf + (size_t)NROWS * DMODEL;     // 24*4096*64
  ushort_t* kh    = qh + (size_t)NBH * NTOK * HD;
  ushort_t* vt    = kh + (size_t)NBH * NTOK * HD;     // V transposed [bh][64][4096]
  ushort_t* opart = vt + (size_t)NBH * NTOK * HD;     // 2*24*4096*64 bf16
  float*    lpart = (float*)(opart + (size_t)2 * NBH * NTOK * HD);  // 2*24*4096 fp32
  // total ~81 MB

  transpose_w4<<<dim3(24, 24, 4), 256, 0, stream>>>(wq, wk, wv, wo, wqkvT, woutT);
  convert_x<<<6144, 256, 0, stream>>>(x, xbf);

  gemm_bt<<<dim3(64, 18), 256, 0, stream>>>(xbf, wqkvT, DMODEL, 0,
                                            qh, kh, vt, nullptr, nullptr);
  attn5<<<dim3(24, 16, 2), 256, 0, stream>>>(qh, kh, vt, opart, lpart);
  combine<<<(NBH * NTOK) / 16, 256, 0, stream>>>(opart, lpart, xbf /*ctx*/);
  gemm_bt<<<dim3(64, 6), 256, 0, stream>>>(xbf, woutT, DMODEL, 1,
                                           nullptr, nullptr, nullptr, out, bo);
}